// Round 8
// baseline (658.204 us; speedup 1.0000x reference)
//
#include <hip/hip_runtime.h>
#include <math.h>

#define NN 100000
#define NE 1200000
#define CC 64
#define GG 256
#define RR 8
#define EPSF 1e-5f
#define BINS 782          // ceil(NN/128), bin = dst >> 7
#define BINP 1024         // padded bin count (pow2 for scan)
#define EPB 4688          // edges per phase1/hist block (256 blocks)
#define WQ 2052           // passA per-quarter LDS stride (pad -> distinct banks)

// ---------- hist: global per-bin edge counts ----------
__global__ __launch_bounds__(256) void k_hist(const int* __restrict__ ei,
                                              int* __restrict__ bin_total) {
  __shared__ int hist[BINP];
  for (int t = threadIdx.x; t < BINP; t += 256) hist[t] = 0;
  __syncthreads();
  int start = blockIdx.x * EPB;
  int end = start + EPB < NE ? start + EPB : NE;
  for (int e = start + threadIdx.x; e < end; e += 256)
    atomicAdd(&hist[ei[NE + e] >> 7], 1);
  __syncthreads();
  for (int t = threadIdx.x; t < BINP; t += 256)
    if (hist[t]) atomicAdd(&bin_total[t], hist[t]);
}

// ---------- scan bins -> bin_base (exclusive), cursor ----------
__global__ __launch_bounds__(1024) void k_scanbins(const int* __restrict__ bin_total,
                                                   int* __restrict__ bin_base,
                                                   int* __restrict__ cursor) {
  __shared__ int sh[BINP];
  int t = threadIdx.x;
  int v = t < BINS ? bin_total[t] : 0;
  sh[t] = v;
  __syncthreads();
  for (int d = 1; d < BINP; d <<= 1) {
    int val = sh[t];
    int add = (t >= d) ? sh[t - d] : 0;
    __syncthreads();
    sh[t] = val + add;
    __syncthreads();
  }
  int excl = sh[t] - v;
  if (t < BINS) {
    bin_base[t] = excl;
    cursor[t] = excl;
  }
  if (t == 0) bin_base[BINS] = NE;
}

// ---------- phase1: scatter (src,dst) pairs into bin-contiguous buckets ----------
__global__ __launch_bounds__(256) void k_phase1(const int* __restrict__ ei,
                                                int* __restrict__ cursor,
                                                uint2* __restrict__ pairs) {
  __shared__ int hist[BINP];
  __shared__ int base[BINP];
  for (int t = threadIdx.x; t < BINP; t += 256) hist[t] = 0;
  __syncthreads();
  int start = blockIdx.x * EPB;
  int end = start + EPB < NE ? start + EPB : NE;
  for (int e = start + threadIdx.x; e < end; e += 256)
    atomicAdd(&hist[ei[NE + e] >> 7], 1);
  __syncthreads();
  for (int t = threadIdx.x; t < BINP; t += 256) {
    int c = hist[t];
    base[t] = c ? atomicAdd(&cursor[t], c) : 0;
  }
  __syncthreads();
  for (int t = threadIdx.x; t < BINP; t += 256) hist[t] = 0;
  __syncthreads();
  for (int e = start + threadIdx.x; e < end; e += 256) {
    int src = ei[e], dst = ei[NE + e];
    int b = dst >> 7;
    int off = atomicAdd(&hist[b], 1);
    pairs[base[b] + off] = make_uint2((unsigned)src, (unsigned)dst);
  }
}

// ---------- agg: per-bin LDS accumulation of x rows; writes agg + deg ----------
__global__ __launch_bounds__(256) void k_agg(const float* __restrict__ x,
                                             const uint2* __restrict__ pairs,
                                             const int* __restrict__ bin_base,
                                             float* __restrict__ h,
                                             float* __restrict__ degf) {
  __shared__ float acc[128 * CC];  // 32 KB
  __shared__ int degl[128];
  for (int t = threadIdx.x; t < 128 * CC; t += 256) acc[t] = 0.0f;
  for (int t = threadIdx.x; t < 128; t += 256) degl[t] = 0;
  __syncthreads();
  int b = blockIdx.x;
  int s = bin_base[b], e = bin_base[b + 1];
  int w = threadIdx.x >> 6;
  int lane = threadIdx.x & 63;
  int sub = lane >> 4;   // 4 edges per wave per iter
  int li = lane & 15;    // 16 lanes per edge, float4 each
  for (int ei_ = s + w * 4 + sub; ei_ < e; ei_ += 16) {
    uint2 pr = pairs[ei_];
    int src = (int)pr.x;
    int dl = (int)pr.y & 127;
    float4 v = *(const float4*)(x + (size_t)src * CC + li * 4);
    float* ap = acc + dl * CC + li * 4;
    atomicAdd(ap + 0, v.x);
    atomicAdd(ap + 1, v.y);
    atomicAdd(ap + 2, v.z);
    atomicAdd(ap + 3, v.w);
    if (li == 0) atomicAdd(&degl[dl], 1);
  }
  __syncthreads();
  int node0 = b << 7;
  for (int idx = threadIdx.x; idx < 128 * 16; idx += 256) {
    int row = idx >> 4, q = idx & 15;
    int node = node0 + row;
    if (node < NN) {
      const float* ap = acc + row * CC + q * 4;
      *(float4*)(h + (size_t)node * CC + q * 4) =
          make_float4(ap[0], ap[1], ap[2], ap[3]);
    }
  }
  for (int row = threadIdx.x; row < 128; row += 256) {
    int node = node0 + row;
    if (node < NN) degf[node] = (float)degl[row];
  }
}

// ---------- passA: h = (agg/deg)@Wl^T + bl + x@Wr^T, in place over h ----------
// Wave-tile = 32 nodes. Lane l: nodes n=l&15 and n+16; output quarter q=l>>4.
__global__ __launch_bounds__(256) void k_passA(
    const float* __restrict__ x, float* h, const float* __restrict__ degf,
    const float* __restrict__ Wl, const float* __restrict__ bl,
    const float* __restrict__ Wr) {
  __shared__ float Ws[4 * WQ];
  __shared__ float bls[CC];
  for (int idx = threadIdx.x; idx < CC * CC; idx += 256) {
    int q = idx >> 10, j = (idx >> 6) & 15, k = idx & 63;
    Ws[q * WQ + j * 128 + 2 * k]     = Wl[idx];
    Ws[q * WQ + j * 128 + 2 * k + 1] = Wr[idx];
  }
  if (threadIdx.x < CC) bls[threadIdx.x] = bl[threadIdx.x];
  __syncthreads();

  int lane = threadIdx.x & 63;
  int wave = threadIdx.x >> 6;
  int n = lane & 15;
  int q = lane >> 4;
  int iA = blockIdx.x * 128 + wave * 32 + n;
  int iB = iA + 16;
  int cA = iA < NN ? iA : NN - 1;
  int cB = iB < NN ? iB : NN - 1;
  float invA = 1.0f / fmaxf(degf[cA], 1.0f);
  float invB = 1.0f / fmaxf(degf[cB], 1.0f);
  const float4* apA = (const float4*)(h + (size_t)cA * CC);
  const float4* xpA = (const float4*)(x + (size_t)cA * CC);
  const float4* apB = (const float4*)(h + (size_t)cB * CC);
  const float4* xpB = (const float4*)(x + (size_t)cB * CC);
  const float4* wq = (const float4*)Ws + q * (WQ / 4);

  float accA[16], accB[16];
#pragma unroll
  for (int j = 0; j < 16; ++j) {
    float b = bls[q * 16 + j];
    accA[j] = b; accB[j] = b;
  }

#pragma unroll 2
  for (int kb = 0; kb < 16; ++kb) {
    float4 aA = apA[kb], xA = xpA[kb];
    float4 aB = apB[kb], xB = xpB[kb];
    float a0A = aA.x * invA, a1A = aA.y * invA, a2A = aA.z * invA, a3A = aA.w * invA;
    float a0B = aB.x * invB, a1B = aB.y * invB, a2B = aB.z * invB, a3B = aB.w * invB;
#pragma unroll
    for (int j = 0; j < 16; ++j) {
      float4 w0 = wq[j * 32 + kb * 2];
      float4 w1 = wq[j * 32 + kb * 2 + 1];
      float tA = accA[j], tB = accB[j];
      tA = fmaf(a0A, w0.x, tA); tB = fmaf(a0B, w0.x, tB);
      tA = fmaf(xA.x, w0.y, tA); tB = fmaf(xB.x, w0.y, tB);
      tA = fmaf(a1A, w0.z, tA); tB = fmaf(a1B, w0.z, tB);
      tA = fmaf(xA.y, w0.w, tA); tB = fmaf(xB.y, w0.w, tB);
      tA = fmaf(a2A, w1.x, tA); tB = fmaf(a2B, w1.x, tB);
      tA = fmaf(xA.z, w1.y, tA); tB = fmaf(xB.z, w1.y, tB);
      tA = fmaf(a3A, w1.z, tA); tB = fmaf(a3B, w1.z, tB);
      tA = fmaf(xA.w, w1.w, tA); tB = fmaf(xB.w, w1.w, tB);
      accA[j] = tA; accB[j] = tB;
    }
  }
  if (iA < NN) {
    float4* hp = (float4*)(h + (size_t)iA * CC + q * 16);
#pragma unroll
    for (int r = 0; r < 4; ++r)
      hp[r] = make_float4(accA[4 * r], accA[4 * r + 1], accA[4 * r + 2], accA[4 * r + 3]);
  }
  if (iB < NN) {
    float4* hp = (float4*)(h + (size_t)iB * CC + q * 16);
#pragma unroll
    for (int r = 0; r < 4; ++r)
      hp[r] = make_float4(accB[4 * r], accB[4 * r + 1], accB[4 * r + 2], accB[4 * r + 3]);
  }
}

// ---------- stats: segmented per-graph sum(h), sum(h^2), count (batch sorted) ----------
__global__ __launch_bounds__(256) void k_stats(const float* __restrict__ h,
                                               const int* __restrict__ batch,
                                               float* __restrict__ sumH,
                                               float* __restrict__ sumH2,
                                               float* __restrict__ cntg) {
  int w = blockIdx.x * 4 + (threadIdx.x >> 6);
  int lane = threadIdx.x & 63;
  int i0 = w * 64;
  if (i0 >= NN) return;
  int iend = i0 + 64 < NN ? i0 + 64 : NN;
  int gcur = batch[i0];
  float aH = 0.0f, aH2 = 0.0f;
  int run = 0;
  for (int i = i0; i < iend; ++i) {
    int g = batch[i];  // wave-uniform
    if (g != gcur) {
      atomicAdd(&sumH[(size_t)gcur * CC + lane], aH);
      atomicAdd(&sumH2[(size_t)gcur * CC + lane], aH2);
      if (lane == 0) atomicAdd(&cntg[gcur], (float)run);
      aH = 0.0f; aH2 = 0.0f; run = 0;
      gcur = g;
    }
    float v = h[(size_t)i * CC + lane];
    aH += v;
    aH2 += v * v;
    run++;
  }
  atomicAdd(&sumH[(size_t)gcur * CC + lane], aH);
  atomicAdd(&sumH2[(size_t)gcur * CC + lane], aH2);
  if (lane == 0) atomicAdd(&cntg[gcur], (float)run);
}

// ---------- passC: normalize (closed-form var) + gate + residual + relu ----------
__global__ __launch_bounds__(256) void k_passC(
    const float* __restrict__ h, const float* __restrict__ x,
    const int* __restrict__ batch, const float* __restrict__ sumH,
    const float* __restrict__ sumH2, const float* __restrict__ cntg,
    const float* __restrict__ gw, const float* __restrict__ gb,
    const float* __restrict__ alpha, const float* __restrict__ a1w,
    const float* __restrict__ a1b, const float* __restrict__ a2w,
    const float* __restrict__ a2b, float* __restrict__ out) {
  __shared__ float A1[RR * CC];
  __shared__ float A2[CC * RR];
  __shared__ float A1B[RR];
  __shared__ float PRM[4 * CC];   // a2b | gw | gb | alpha
  for (int idx = threadIdx.x; idx < RR * CC; idx += 256) {
    A1[idx] = a1w[idx];
    A2[idx] = a2w[idx];
  }
  if (threadIdx.x < RR) A1B[threadIdx.x] = a1b[threadIdx.x];
  if (threadIdx.x < CC) {
    PRM[threadIdx.x] = a2b[threadIdx.x];
    PRM[CC + threadIdx.x] = gw[threadIdx.x];
    PRM[2 * CC + threadIdx.x] = gb[threadIdx.x];
    PRM[3 * CC + threadIdx.x] = alpha[threadIdx.x];
  }
  __syncthreads();

  int i = blockIdx.x * 256 + threadIdx.x;
  if (i >= NN) return;
  int g = batch[i];
  float rn = 1.0f / fmaxf(cntg[g], 1.0f);
  float xv[CC];
  const float4* xp = (const float4*)(x + (size_t)i * CC);
#pragma unroll
  for (int q = 0; q < 16; ++q) {
    float4 b = xp[q];
    xv[4 * q] = b.x; xv[4 * q + 1] = b.y; xv[4 * q + 2] = b.z; xv[4 * q + 3] = b.w;
  }
  float p[RR];
#pragma unroll
  for (int r = 0; r < RR; ++r) {
    float acc = A1B[r];
#pragma unroll
    for (int k = 0; k < CC; ++k) acc = fmaf(xv[k], A1[r * CC + k], acc);
    p[r] = fmaxf(acc, 0.0f);
  }
  const float4* hp = (const float4*)(h + (size_t)i * CC);
  const float4* sHp = (const float4*)(sumH + (size_t)g * CC);
  const float4* sH2p = (const float4*)(sumH2 + (size_t)g * CC);
  float4* op = (float4*)(out + (size_t)i * CC);
#pragma unroll 4
  for (int q = 0; q < 16; ++q) {
    float4 h4 = hp[q];
    float4 sH = sHp[q];
    float4 sH2 = sH2p[q];
    float hv[4] = {h4.x, h4.y, h4.z, h4.w};
    float sh[4] = {sH.x, sH.y, sH.z, sH.w};
    float sh2[4] = {sH2.x, sH2.y, sH2.z, sH2.w};
    float res[4];
#pragma unroll
    for (int u = 0; u < 4; ++u) {
      int c = q * 4 + u;
      float mu = sh[u] * rn;
      float t = PRM[3 * CC + c] * mu;
      float var = sh2[u] * rn - 2.0f * mu * t + t * t;
      float o = hv[u] - t;
      float y = fmaf(PRM[CC + c] * o, rsqrtf(var + EPSF), PRM[2 * CC + c]);
      float gacc = PRM[c];
#pragma unroll
      for (int r = 0; r < RR; ++r) gacc = fmaf(p[r], A2[c * RR + r], gacc);
      float gate = 1.0f / (1.0f + __expf(-gacc));
      res[u] = fmaxf(y + gate * xv[c], 0.0f);
    }
    op[q] = make_float4(res[0], res[1], res[2], res[3]);
  }
}

extern "C" void kernel_launch(void* const* d_in, const int* in_sizes, int n_in,
                              void* d_out, int out_size, void* d_ws, size_t ws_size,
                              hipStream_t stream) {
  const float* x        = (const float*)d_in[0];
  const int*   ei       = (const int*)d_in[1];
  const int*   batch    = (const int*)d_in[2];
  const float* Wl       = (const float*)d_in[3];
  const float* bl       = (const float*)d_in[4];
  const float* Wr       = (const float*)d_in[5];
  const float* gn_w     = (const float*)d_in[6];
  const float* gn_b     = (const float*)d_in[7];
  const float* gn_alpha = (const float*)d_in[8];
  const float* a1w      = (const float*)d_in[9];
  const float* a1b      = (const float*)d_in[10];
  const float* a2w      = (const float*)d_in[11];
  const float* a2b      = (const float*)d_in[12];
  float* out = (float*)d_out;

  // workspace layout (4B units)
  float* h        = (float*)d_ws;                      // NN*CC
  uint2* pairs    = (uint2*)(h + (size_t)NN * CC);     // NE uint2 (8B-aligned)
  float* degf     = (float*)(pairs + NE);              // NN
  int*   bin_tot  = (int*)(degf + NN);                 // BINP  } zeroed
  float* sumH     = (float*)(bin_tot + BINP);          // GG*CC } zeroed
  float* sumH2    = sumH + GG * CC;                    // GG*CC } zeroed
  float* cntg     = sumH2 + GG * CC;                   // GG    } zeroed
  int*   bin_base = (int*)(cntg + GG);                 // BINS+1
  int*   cursor   = bin_base + BINS + 1;               // BINS

  size_t zbytes = ((size_t)BINP + 2 * GG * CC + GG) * sizeof(int);
  hipMemsetAsync((void*)bin_tot, 0, zbytes, stream);

  k_hist    <<<256, 256, 0, stream>>>(ei, bin_tot);
  k_scanbins<<<1, BINP, 0, stream>>>(bin_tot, bin_base, cursor);
  k_phase1  <<<256, 256, 0, stream>>>(ei, cursor, pairs);
  k_agg     <<<BINS, 256, 0, stream>>>(x, pairs, bin_base, h, degf);
  k_passA   <<<(NN + 127) / 128, 256, 0, stream>>>(x, h, degf, Wl, bl, Wr);
  k_stats   <<<((NN + 63) / 64 + 3) / 4, 256, 0, stream>>>(h, batch, sumH, sumH2, cntg);
  k_passC   <<<(NN + 255) / 256, 256, 0, stream>>>(h, x, batch, sumH, sumH2, cntg,
                                                   gn_w, gn_b, gn_alpha,
                                                   a1w, a1b, a2w, a2b, out);
}

// Round 9
// 220.653 us; speedup vs baseline: 2.9830x; 2.9830x over previous
//
#include <hip/hip_runtime.h>
#include <math.h>

#define NN 100000
#define NE 1200000
#define CC 64
#define GG 256
#define RR 8
#define EPSF 1e-5f
#define BINS 782   // ceil(NN/128), bin = dst >> 7
#define BINP 1024  // padded (pow2)
#define EPB 4688   // edges per hist/phase1 block (256 blocks)
#define WQ 2052    // passA per-quarter LDS stride

// ---------- hist: global per-bin edge counts ----------
__global__ __launch_bounds__(256) void k_hist(const int* __restrict__ ei,
                                              int* __restrict__ bin_total) {
  __shared__ int hist[BINP];
  for (int t = threadIdx.x; t < BINP; t += 256) hist[t] = 0;
  __syncthreads();
  int start = blockIdx.x * EPB;
  int end = start + EPB < NE ? start + EPB : NE;
  for (int e = start + threadIdx.x; e < end; e += 256)
    atomicAdd(&hist[ei[NE + e] >> 7], 1);
  __syncthreads();
  for (int t = threadIdx.x; t < BINP; t += 256)
    if (hist[t]) atomicAdd(&bin_total[t], hist[t]);
}

// ---------- scan bins -> bin_base (exclusive) + cursor; rowptr[NN]=NE ----------
__global__ __launch_bounds__(1024) void k_scanbins(const int* __restrict__ bin_total,
                                                   int* __restrict__ bin_base,
                                                   int* __restrict__ cursor,
                                                   int* __restrict__ rowptr) {
  __shared__ int sh[BINP];
  int t = threadIdx.x;
  int v = t < BINS ? bin_total[t] : 0;
  sh[t] = v;
  __syncthreads();
  for (int d = 1; d < BINP; d <<= 1) {
    int val = sh[t];
    int add = (t >= d) ? sh[t - d] : 0;
    __syncthreads();
    sh[t] = val + add;
    __syncthreads();
  }
  int excl = sh[t] - v;
  if (t < BINS) {
    bin_base[t] = excl;
    cursor[t] = excl;
  }
  if (t == 0) {
    bin_base[BINS] = NE;
    rowptr[NN] = NE;
  }
}

// ---------- phase1: packed (src<<7)|(dst&127) into bin-contiguous buckets ----------
__global__ __launch_bounds__(256) void k_phase1(const int* __restrict__ ei,
                                                int* __restrict__ cursor,
                                                unsigned* __restrict__ ebuf) {
  __shared__ int hist[BINP];
  __shared__ int base[BINP];
  for (int t = threadIdx.x; t < BINP; t += 256) hist[t] = 0;
  __syncthreads();
  int start = blockIdx.x * EPB;
  int end = start + EPB < NE ? start + EPB : NE;
  for (int e = start + threadIdx.x; e < end; e += 256)
    atomicAdd(&hist[ei[NE + e] >> 7], 1);
  __syncthreads();
  for (int t = threadIdx.x; t < BINP; t += 256) {
    int c = hist[t];
    base[t] = c ? atomicAdd(&cursor[t], c) : 0;
  }
  __syncthreads();
  for (int t = threadIdx.x; t < BINP; t += 256) hist[t] = 0;
  __syncthreads();
  for (int e = start + threadIdx.x; e < end; e += 256) {
    int src = ei[e], dst = ei[NE + e];
    int b = dst >> 7;
    int off = atomicAdd(&hist[b], 1);
    ebuf[base[b] + off] = ((unsigned)src << 7) | (unsigned)(dst & 127);
  }
}

// ---------- fill2: per-bin CSR (rowptr + coalesced csr) ----------
__global__ __launch_bounds__(256) void k_fill2(const unsigned* __restrict__ ebuf,
                                               const int* __restrict__ bin_base,
                                               int* __restrict__ rowptr,
                                               int* __restrict__ csr) {
  __shared__ int cnt[128];
  __shared__ int sc[128];
  int tid = threadIdx.x;
  int b = blockIdx.x;
  int s = bin_base[b], e = bin_base[b + 1];
  if (tid < 128) cnt[tid] = 0;
  __syncthreads();
  for (int i = s + tid; i < e; i += 256) atomicAdd(&cnt[ebuf[i] & 127], 1);
  __syncthreads();
  if (tid < 128) sc[tid] = cnt[tid];
  __syncthreads();
  for (int d = 1; d < 128; d <<= 1) {
    int v = (tid < 128) ? sc[tid] : 0;
    int a = (tid >= d && tid < 128) ? sc[tid - d] : 0;
    __syncthreads();
    if (tid < 128) sc[tid] = v + a;
    __syncthreads();
  }
  if (tid < 128) {
    sc[tid] -= cnt[tid];  // exclusive
    int node = (b << 7) + tid;
    if (node < NN) rowptr[node] = s + sc[tid];
    cnt[tid] = 0;
  }
  __syncthreads();
  for (int i = s + tid; i < e; i += 256) {
    unsigned v = ebuf[i];
    int dl = v & 127;
    int off = atomicAdd(&cnt[dl], 1);
    csr[s + sc[dl] + off] = (int)(v >> 7);
  }
}

// ---------- gather: agg[i] = sum of x[src] over in-edges (wave per node) ----------
__global__ __launch_bounds__(256) void k_gather(const float* __restrict__ x,
                                                const int* __restrict__ csr,
                                                const int* __restrict__ rowptr,
                                                float* __restrict__ h) {
  int w = blockIdx.x * 4 + (threadIdx.x >> 6);
  int lane = threadIdx.x & 63;
  if (w >= NN) return;
  int s = rowptr[w], e = rowptr[w + 1];
  float acc = 0.0f;
  int j = s;
  for (; j + 3 < e; j += 4) {
    int s0 = csr[j], s1 = csr[j + 1], s2 = csr[j + 2], s3 = csr[j + 3];
    acc += x[(size_t)s0 * CC + lane];
    acc += x[(size_t)s1 * CC + lane];
    acc += x[(size_t)s2 * CC + lane];
    acc += x[(size_t)s3 * CC + lane];
  }
  for (; j < e; ++j) acc += x[(size_t)csr[j] * CC + lane];
  h[(size_t)w * CC + lane] = acc;
}

// ---------- passA: h = (agg/deg)@Wl^T + bl + x@Wr^T, in place over h ----------
// Wave-tile = 32 nodes. Lane l: nodes n=l&15 and n+16; output quarter q=l>>4.
__global__ __launch_bounds__(256) void k_passA(
    const float* __restrict__ x, float* h, const int* __restrict__ rowptr,
    const float* __restrict__ Wl, const float* __restrict__ bl,
    const float* __restrict__ Wr) {
  __shared__ float Ws[4 * WQ];
  __shared__ float bls[CC];
  for (int idx = threadIdx.x; idx < CC * CC; idx += 256) {
    int q = idx >> 10, j = (idx >> 6) & 15, k = idx & 63;
    Ws[q * WQ + j * 128 + 2 * k]     = Wl[idx];
    Ws[q * WQ + j * 128 + 2 * k + 1] = Wr[idx];
  }
  if (threadIdx.x < CC) bls[threadIdx.x] = bl[threadIdx.x];
  __syncthreads();

  int lane = threadIdx.x & 63;
  int wave = threadIdx.x >> 6;
  int n = lane & 15;
  int q = lane >> 4;
  int iA = blockIdx.x * 128 + wave * 32 + n;
  int iB = iA + 16;
  int cA = iA < NN ? iA : NN - 1;
  int cB = iB < NN ? iB : NN - 1;
  float invA = 1.0f / fmaxf((float)(rowptr[cA + 1] - rowptr[cA]), 1.0f);
  float invB = 1.0f / fmaxf((float)(rowptr[cB + 1] - rowptr[cB]), 1.0f);
  const float4* apA = (const float4*)(h + (size_t)cA * CC);
  const float4* xpA = (const float4*)(x + (size_t)cA * CC);
  const float4* apB = (const float4*)(h + (size_t)cB * CC);
  const float4* xpB = (const float4*)(x + (size_t)cB * CC);
  const float4* wq = (const float4*)Ws + q * (WQ / 4);

  float accA[16], accB[16];
#pragma unroll
  for (int j = 0; j < 16; ++j) {
    float b = bls[q * 16 + j];
    accA[j] = b; accB[j] = b;
  }

#pragma unroll 2
  for (int kb = 0; kb < 16; ++kb) {
    float4 aA = apA[kb], xA = xpA[kb];
    float4 aB = apB[kb], xB = xpB[kb];
    float a0A = aA.x * invA, a1A = aA.y * invA, a2A = aA.z * invA, a3A = aA.w * invA;
    float a0B = aB.x * invB, a1B = aB.y * invB, a2B = aB.z * invB, a3B = aB.w * invB;
#pragma unroll
    for (int j = 0; j < 16; ++j) {
      float4 w0 = wq[j * 32 + kb * 2];
      float4 w1 = wq[j * 32 + kb * 2 + 1];
      float tA = accA[j], tB = accB[j];
      tA = fmaf(a0A, w0.x, tA); tB = fmaf(a0B, w0.x, tB);
      tA = fmaf(xA.x, w0.y, tA); tB = fmaf(xB.x, w0.y, tB);
      tA = fmaf(a1A, w0.z, tA); tB = fmaf(a1B, w0.z, tB);
      tA = fmaf(xA.y, w0.w, tA); tB = fmaf(xB.y, w0.w, tB);
      tA = fmaf(a2A, w1.x, tA); tB = fmaf(a2B, w1.x, tB);
      tA = fmaf(xA.z, w1.y, tA); tB = fmaf(xB.z, w1.y, tB);
      tA = fmaf(a3A, w1.z, tA); tB = fmaf(a3B, w1.z, tB);
      tA = fmaf(xA.w, w1.w, tA); tB = fmaf(xB.w, w1.w, tB);
      accA[j] = tA; accB[j] = tB;
    }
  }
  if (iA < NN) {
    float4* hp = (float4*)(h + (size_t)iA * CC + q * 16);
#pragma unroll
    for (int r = 0; r < 4; ++r)
      hp[r] = make_float4(accA[4 * r], accA[4 * r + 1], accA[4 * r + 2], accA[4 * r + 3]);
  }
  if (iB < NN) {
    float4* hp = (float4*)(h + (size_t)iB * CC + q * 16);
#pragma unroll
    for (int r = 0; r < 4; ++r)
      hp[r] = make_float4(accB[4 * r], accB[4 * r + 1], accB[4 * r + 2], accB[4 * r + 3]);
  }
}

// ---------- stats: segmented per-graph sum(h), sum(h^2), count (batch sorted) ----------
__global__ __launch_bounds__(256) void k_stats(const float* __restrict__ h,
                                               const int* __restrict__ batch,
                                               float* __restrict__ sumH,
                                               float* __restrict__ sumH2,
                                               float* __restrict__ cntg) {
  int w = blockIdx.x * 4 + (threadIdx.x >> 6);
  int lane = threadIdx.x & 63;
  int i0 = w * 64;
  if (i0 >= NN) return;
  int iend = i0 + 64 < NN ? i0 + 64 : NN;
  int gcur = batch[i0];
  float aH = 0.0f, aH2 = 0.0f;
  int run = 0;
  for (int i = i0; i < iend; ++i) {
    int g = batch[i];  // wave-uniform
    if (g != gcur) {
      atomicAdd(&sumH[(size_t)gcur * CC + lane], aH);
      atomicAdd(&sumH2[(size_t)gcur * CC + lane], aH2);
      if (lane == 0) atomicAdd(&cntg[gcur], (float)run);
      aH = 0.0f; aH2 = 0.0f; run = 0;
      gcur = g;
    }
    float v = h[(size_t)i * CC + lane];
    aH += v;
    aH2 += v * v;
    run++;
  }
  atomicAdd(&sumH[(size_t)gcur * CC + lane], aH);
  atomicAdd(&sumH2[(size_t)gcur * CC + lane], aH2);
  if (lane == 0) atomicAdd(&cntg[gcur], (float)run);
}

// ---------- passC: normalize (closed-form var) + gate + residual + relu ----------
__global__ __launch_bounds__(256) void k_passC(
    const float* __restrict__ h, const float* __restrict__ x,
    const int* __restrict__ batch, const float* __restrict__ sumH,
    const float* __restrict__ sumH2, const float* __restrict__ cntg,
    const float* __restrict__ gw, const float* __restrict__ gb,
    const float* __restrict__ alpha, const float* __restrict__ a1w,
    const float* __restrict__ a1b, const float* __restrict__ a2w,
    const float* __restrict__ a2b, float* __restrict__ out) {
  __shared__ float A1[RR * CC];
  __shared__ float A2[CC * RR];
  __shared__ float A1B[RR];
  __shared__ float PRM[4 * CC];   // a2b | gw | gb | alpha
  for (int idx = threadIdx.x; idx < RR * CC; idx += 256) {
    A1[idx] = a1w[idx];
    A2[idx] = a2w[idx];
  }
  if (threadIdx.x < RR) A1B[threadIdx.x] = a1b[threadIdx.x];
  if (threadIdx.x < CC) {
    PRM[threadIdx.x] = a2b[threadIdx.x];
    PRM[CC + threadIdx.x] = gw[threadIdx.x];
    PRM[2 * CC + threadIdx.x] = gb[threadIdx.x];
    PRM[3 * CC + threadIdx.x] = alpha[threadIdx.x];
  }
  __syncthreads();

  int i = blockIdx.x * 256 + threadIdx.x;
  if (i >= NN) return;
  int g = batch[i];
  float rn = 1.0f / fmaxf(cntg[g], 1.0f);
  float xv[CC];
  const float4* xp = (const float4*)(x + (size_t)i * CC);
#pragma unroll
  for (int q = 0; q < 16; ++q) {
    float4 b = xp[q];
    xv[4 * q] = b.x; xv[4 * q + 1] = b.y; xv[4 * q + 2] = b.z; xv[4 * q + 3] = b.w;
  }
  float p[RR];
#pragma unroll
  for (int r = 0; r < RR; ++r) {
    float acc = A1B[r];
#pragma unroll
    for (int k = 0; k < CC; ++k) acc = fmaf(xv[k], A1[r * CC + k], acc);
    p[r] = fmaxf(acc, 0.0f);
  }
  const float4* hp = (const float4*)(h + (size_t)i * CC);
  const float4* sHp = (const float4*)(sumH + (size_t)g * CC);
  const float4* sH2p = (const float4*)(sumH2 + (size_t)g * CC);
  float4* op = (float4*)(out + (size_t)i * CC);
#pragma unroll 4
  for (int q = 0; q < 16; ++q) {
    float4 h4 = hp[q];
    float4 sH = sHp[q];
    float4 sH2 = sH2p[q];
    float hv[4] = {h4.x, h4.y, h4.z, h4.w};
    float sh[4] = {sH.x, sH.y, sH.z, sH.w};
    float sh2[4] = {sH2.x, sH2.y, sH2.z, sH2.w};
    float res[4];
#pragma unroll
    for (int u = 0; u < 4; ++u) {
      int c = q * 4 + u;
      float mu = sh[u] * rn;
      float t = PRM[3 * CC + c] * mu;
      float var = sh2[u] * rn - 2.0f * mu * t + t * t;
      float o = hv[u] - t;
      float y = fmaf(PRM[CC + c] * o, rsqrtf(var + EPSF), PRM[2 * CC + c]);
      float gacc = PRM[c];
#pragma unroll
      for (int r = 0; r < RR; ++r) gacc = fmaf(p[r], A2[c * RR + r], gacc);
      float gate = 1.0f / (1.0f + __expf(-gacc));
      res[u] = fmaxf(y + gate * xv[c], 0.0f);
    }
    op[q] = make_float4(res[0], res[1], res[2], res[3]);
  }
}

extern "C" void kernel_launch(void* const* d_in, const int* in_sizes, int n_in,
                              void* d_out, int out_size, void* d_ws, size_t ws_size,
                              hipStream_t stream) {
  const float* x        = (const float*)d_in[0];
  const int*   ei       = (const int*)d_in[1];
  const int*   batch    = (const int*)d_in[2];
  const float* Wl       = (const float*)d_in[3];
  const float* bl       = (const float*)d_in[4];
  const float* Wr       = (const float*)d_in[5];
  const float* gn_w     = (const float*)d_in[6];
  const float* gn_b     = (const float*)d_in[7];
  const float* gn_alpha = (const float*)d_in[8];
  const float* a1w      = (const float*)d_in[9];
  const float* a1b      = (const float*)d_in[10];
  const float* a2w      = (const float*)d_in[11];
  const float* a2b      = (const float*)d_in[12];
  float* out = (float*)d_out;

  // workspace layout (4B units)
  float*    h        = (float*)d_ws;                   // NN*CC
  unsigned* ebuf     = (unsigned*)(h + (size_t)NN * CC); // NE
  int*      csr      = (int*)(ebuf + NE);              // NE
  int*      rowptr   = csr + NE;                       // NN+1
  int*      bin_tot  = rowptr + NN + 1;                // BINP  } zeroed
  float*    sumH     = (float*)(bin_tot + BINP);       // GG*CC } zeroed
  float*    sumH2    = sumH + GG * CC;                 // GG*CC } zeroed
  float*    cntg     = sumH2 + GG * CC;                // GG    } zeroed
  int*      bin_base = (int*)(cntg + GG);              // BINS+1
  int*      cursor   = bin_base + BINS + 1;            // BINS

  size_t zbytes = ((size_t)BINP + 2 * GG * CC + GG) * sizeof(int);
  hipMemsetAsync((void*)bin_tot, 0, zbytes, stream);

  k_hist    <<<256, 256, 0, stream>>>(ei, bin_tot);
  k_scanbins<<<1, BINP, 0, stream>>>(bin_tot, bin_base, cursor, rowptr);
  k_phase1  <<<256, 256, 0, stream>>>(ei, cursor, ebuf);
  k_fill2   <<<BINS, 256, 0, stream>>>(ebuf, bin_base, rowptr, csr);
  k_gather  <<<(NN + 3) / 4, 256, 0, stream>>>(x, csr, rowptr, h);
  k_passA   <<<(NN + 127) / 128, 256, 0, stream>>>(x, h, rowptr, Wl, bl, Wr);
  k_stats   <<<((NN + 63) / 64 + 3) / 4, 256, 0, stream>>>(h, batch, sumH, sumH2, cntg);
  k_passC   <<<(NN + 255) / 256, 256, 0, stream>>>(h, x, batch, sumH, sumH2, cntg,
                                                   gn_w, gn_b, gn_alpha,
                                                   a1w, a1b, a2w, a2b, out);
}

// Round 10
// 219.458 us; speedup vs baseline: 2.9992x; 1.0054x over previous
//
#include <hip/hip_runtime.h>
#include <math.h>

#define NN 100000
#define NE 1200000
#define CC 64
#define GG 256
#define RR 8
#define EPSF 1e-5f
#define BINS 782   // ceil(NN/128), bin = dst >> 7
#define BINP 1024  // padded (pow2)
#define EPB 4688   // edges per hist/phase1 block (256 blocks)
#define WQ 2052    // passA per-quarter LDS stride

// ---------- hist: global per-bin edge counts ----------
__global__ __launch_bounds__(256) void k_hist(const int* __restrict__ ei,
                                              int* __restrict__ bin_total) {
  __shared__ int hist[BINP];
  for (int t = threadIdx.x; t < BINP; t += 256) hist[t] = 0;
  __syncthreads();
  int start = blockIdx.x * EPB;
  int end = start + EPB < NE ? start + EPB : NE;
  for (int e = start + threadIdx.x; e < end; e += 256)
    atomicAdd(&hist[ei[NE + e] >> 7], 1);
  __syncthreads();
  for (int t = threadIdx.x; t < BINP; t += 256)
    if (hist[t]) atomicAdd(&bin_total[t], hist[t]);
}

// ---------- scan bins -> bin_base (exclusive) + cursor; rowptr[NN]=NE ----------
__global__ __launch_bounds__(1024) void k_scanbins(const int* __restrict__ bin_total,
                                                   int* __restrict__ bin_base,
                                                   int* __restrict__ cursor,
                                                   int* __restrict__ rowptr) {
  __shared__ int sh[BINP];
  int t = threadIdx.x;
  int v = t < BINS ? bin_total[t] : 0;
  sh[t] = v;
  __syncthreads();
  for (int d = 1; d < BINP; d <<= 1) {
    int val = sh[t];
    int add = (t >= d) ? sh[t - d] : 0;
    __syncthreads();
    sh[t] = val + add;
    __syncthreads();
  }
  int excl = sh[t] - v;
  if (t < BINS) {
    bin_base[t] = excl;
    cursor[t] = excl;
  }
  if (t == 0) {
    bin_base[BINS] = NE;
    rowptr[NN] = NE;
  }
}

// ---------- phase1: packed (src<<7)|(dst&127) into bin-contiguous buckets ----------
__global__ __launch_bounds__(256) void k_phase1(const int* __restrict__ ei,
                                                int* __restrict__ cursor,
                                                unsigned* __restrict__ ebuf) {
  __shared__ int hist[BINP];
  __shared__ int base[BINP];
  for (int t = threadIdx.x; t < BINP; t += 256) hist[t] = 0;
  __syncthreads();
  int start = blockIdx.x * EPB;
  int end = start + EPB < NE ? start + EPB : NE;
  for (int e = start + threadIdx.x; e < end; e += 256)
    atomicAdd(&hist[ei[NE + e] >> 7], 1);
  __syncthreads();
  for (int t = threadIdx.x; t < BINP; t += 256) {
    int c = hist[t];
    base[t] = c ? atomicAdd(&cursor[t], c) : 0;
  }
  __syncthreads();
  for (int t = threadIdx.x; t < BINP; t += 256) hist[t] = 0;
  __syncthreads();
  for (int e = start + threadIdx.x; e < end; e += 256) {
    int src = ei[e], dst = ei[NE + e];
    int b = dst >> 7;
    int off = atomicAdd(&hist[b], 1);
    ebuf[base[b] + off] = ((unsigned)src << 7) | (unsigned)(dst & 127);
  }
}

// ---------- fill2: per-bin CSR (rowptr + coalesced csr) ----------
__global__ __launch_bounds__(256) void k_fill2(const unsigned* __restrict__ ebuf,
                                               const int* __restrict__ bin_base,
                                               int* __restrict__ rowptr,
                                               int* __restrict__ csr) {
  __shared__ int cnt[128];
  __shared__ int sc[128];
  int tid = threadIdx.x;
  int b = blockIdx.x;
  int s = bin_base[b], e = bin_base[b + 1];
  if (tid < 128) cnt[tid] = 0;
  __syncthreads();
  for (int i = s + tid; i < e; i += 256) atomicAdd(&cnt[ebuf[i] & 127], 1);
  __syncthreads();
  if (tid < 128) sc[tid] = cnt[tid];
  __syncthreads();
  for (int d = 1; d < 128; d <<= 1) {
    int v = (tid < 128) ? sc[tid] : 0;
    int a = (tid >= d && tid < 128) ? sc[tid - d] : 0;
    __syncthreads();
    if (tid < 128) sc[tid] = v + a;
    __syncthreads();
  }
  if (tid < 128) {
    sc[tid] -= cnt[tid];  // exclusive
    int node = (b << 7) + tid;
    if (node < NN) rowptr[node] = s + sc[tid];
    cnt[tid] = 0;
  }
  __syncthreads();
  for (int i = s + tid; i < e; i += 256) {
    unsigned v = ebuf[i];
    int dl = v & 127;
    int off = atomicAdd(&cnt[dl], 1);
    csr[s + sc[dl] + off] = (int)(v >> 7);
  }
}

// ---------- gather: agg[i] = sum of x[src] (wave per node, 8-deep MLP) ----------
__global__ __launch_bounds__(256) void k_gather(const float* __restrict__ x,
                                                const int* __restrict__ csr,
                                                const int* __restrict__ rowptr,
                                                float* __restrict__ h) {
  int w = blockIdx.x * 4 + (threadIdx.x >> 6);
  int lane = threadIdx.x & 63;
  if (w >= NN) return;
  int s = rowptr[w], e = rowptr[w + 1];
  float acc = 0.0f;
  for (int j0 = s; j0 < e; j0 += 8) {
    int idx[8];
#pragma unroll
    for (int u = 0; u < 8; ++u) {
      int j = j0 + u;
      idx[u] = csr[j < e ? j : e - 1];  // wave-uniform -> s_load
    }
    float v[8];
#pragma unroll
    for (int u = 0; u < 8; ++u) v[u] = x[(size_t)idx[u] * CC + lane];
#pragma unroll
    for (int u = 0; u < 8; ++u) acc += (j0 + u < e) ? v[u] : 0.0f;
  }
  h[(size_t)w * CC + lane] = acc;
}

// ---------- passA: h = (agg/deg)@Wl^T + bl + x@Wr^T, in place over h ----------
// Wave-tile = 64 nodes. Lane l: nodes n, n+16, n+32, n+48 (n=l&15), output
// quarter q=l>>4. acc[4][16] static-indexed (64 regs, no spill). Each weight
// ds_read_b128 feeds 32 FMAs (2x fewer LDS reads/node than 32-node tile).
__global__ __launch_bounds__(256) void k_passA(
    const float* __restrict__ x, float* h, const int* __restrict__ rowptr,
    const float* __restrict__ Wl, const float* __restrict__ bl,
    const float* __restrict__ Wr) {
  __shared__ float Ws[4 * WQ];
  __shared__ float bls[CC];
  for (int idx = threadIdx.x; idx < CC * CC; idx += 256) {
    int q = idx >> 10, j = (idx >> 6) & 15, k = idx & 63;
    Ws[q * WQ + j * 128 + 2 * k]     = Wl[idx];
    Ws[q * WQ + j * 128 + 2 * k + 1] = Wr[idx];
  }
  if (threadIdx.x < CC) bls[threadIdx.x] = bl[threadIdx.x];
  __syncthreads();

  int lane = threadIdx.x & 63;
  int wave = threadIdx.x >> 6;
  int n = lane & 15;
  int q = lane >> 4;
  int i0 = blockIdx.x * 256 + wave * 64 + n;  // + m*16
  const float4* wq = (const float4*)Ws + q * (WQ / 4);

  const float4* ap[4];
  const float4* xp[4];
  float inv[4];
#pragma unroll
  for (int m = 0; m < 4; ++m) {
    int i = i0 + m * 16;
    int c = i < NN ? i : NN - 1;
    inv[m] = 1.0f / fmaxf((float)(rowptr[c + 1] - rowptr[c]), 1.0f);
    ap[m] = (const float4*)(h + (size_t)c * CC);
    xp[m] = (const float4*)(x + (size_t)c * CC);
  }

  float acc[4][16];
#pragma unroll
  for (int j = 0; j < 16; ++j) {
    float b = bls[q * 16 + j];
#pragma unroll
    for (int m = 0; m < 4; ++m) acc[m][j] = b;
  }

  for (int kb = 0; kb < 16; ++kb) {
    float4 xv[4];
    float a0[4], a1[4], a2[4], a3[4];
#pragma unroll
    for (int m = 0; m < 4; ++m) {
      float4 av = ap[m][kb];
      xv[m] = xp[m][kb];
      a0[m] = av.x * inv[m]; a1[m] = av.y * inv[m];
      a2[m] = av.z * inv[m]; a3[m] = av.w * inv[m];
    }
#pragma unroll
    for (int j = 0; j < 16; ++j) {
      float4 w0 = wq[j * 32 + kb * 2];
      float4 w1 = wq[j * 32 + kb * 2 + 1];
#pragma unroll
      for (int m = 0; m < 4; ++m) {
        float t = acc[m][j];
        t = fmaf(a0[m], w0.x, t);
        t = fmaf(xv[m].x, w0.y, t);
        t = fmaf(a1[m], w0.z, t);
        t = fmaf(xv[m].y, w0.w, t);
        t = fmaf(a2[m], w1.x, t);
        t = fmaf(xv[m].z, w1.y, t);
        t = fmaf(a3[m], w1.z, t);
        t = fmaf(xv[m].w, w1.w, t);
        acc[m][j] = t;
      }
    }
  }
#pragma unroll
  for (int m = 0; m < 4; ++m) {
    int i = i0 + m * 16;
    if (i < NN) {
      float4* hp = (float4*)(h + (size_t)i * CC + q * 16);
#pragma unroll
      for (int r = 0; r < 4; ++r)
        hp[r] = make_float4(acc[m][4 * r], acc[m][4 * r + 1],
                            acc[m][4 * r + 2], acc[m][4 * r + 3]);
    }
  }
}

// ---------- stats: segmented per-graph sum(h), sum(h^2), count (batch sorted) ----------
__global__ __launch_bounds__(256) void k_stats(const float* __restrict__ h,
                                               const int* __restrict__ batch,
                                               float* __restrict__ sumH,
                                               float* __restrict__ sumH2,
                                               float* __restrict__ cntg) {
  int w = blockIdx.x * 4 + (threadIdx.x >> 6);
  int lane = threadIdx.x & 63;
  int i0 = w * 16;
  if (i0 >= NN) return;
  int iend = i0 + 16 < NN ? i0 + 16 : NN;
  int gcur = batch[i0];
  float aH = 0.0f, aH2 = 0.0f;
  int run = 0;
  for (int i = i0; i < iend; ++i) {
    int g = batch[i];  // wave-uniform
    if (g != gcur) {
      atomicAdd(&sumH[(size_t)gcur * CC + lane], aH);
      atomicAdd(&sumH2[(size_t)gcur * CC + lane], aH2);
      if (lane == 0) atomicAdd(&cntg[gcur], (float)run);
      aH = 0.0f; aH2 = 0.0f; run = 0;
      gcur = g;
    }
    float v = h[(size_t)i * CC + lane];
    aH += v;
    aH2 += v * v;
    run++;
  }
  atomicAdd(&sumH[(size_t)gcur * CC + lane], aH);
  atomicAdd(&sumH2[(size_t)gcur * CC + lane], aH2);
  if (lane == 0) atomicAdd(&cntg[gcur], (float)run);
}

// ---------- passC: normalize (closed-form var) + gate + residual + relu ----------
__global__ __launch_bounds__(256) void k_passC(
    const float* __restrict__ h, const float* __restrict__ x,
    const int* __restrict__ batch, const float* __restrict__ sumH,
    const float* __restrict__ sumH2, const float* __restrict__ cntg,
    const float* __restrict__ gw, const float* __restrict__ gb,
    const float* __restrict__ alpha, const float* __restrict__ a1w,
    const float* __restrict__ a1b, const float* __restrict__ a2w,
    const float* __restrict__ a2b, float* __restrict__ out) {
  __shared__ float A1[RR * CC];
  __shared__ float A2[CC * RR];
  __shared__ float A1B[RR];
  __shared__ float PRM[4 * CC];   // a2b | gw | gb | alpha
  for (int idx = threadIdx.x; idx < RR * CC; idx += 256) {
    A1[idx] = a1w[idx];
    A2[idx] = a2w[idx];
  }
  if (threadIdx.x < RR) A1B[threadIdx.x] = a1b[threadIdx.x];
  if (threadIdx.x < CC) {
    PRM[threadIdx.x] = a2b[threadIdx.x];
    PRM[CC + threadIdx.x] = gw[threadIdx.x];
    PRM[2 * CC + threadIdx.x] = gb[threadIdx.x];
    PRM[3 * CC + threadIdx.x] = alpha[threadIdx.x];
  }
  __syncthreads();

  int i = blockIdx.x * 256 + threadIdx.x;
  if (i >= NN) return;
  int g = batch[i];
  float rn = 1.0f / fmaxf(cntg[g], 1.0f);
  float xv[CC];
  const float4* xp = (const float4*)(x + (size_t)i * CC);
#pragma unroll
  for (int q = 0; q < 16; ++q) {
    float4 b = xp[q];
    xv[4 * q] = b.x; xv[4 * q + 1] = b.y; xv[4 * q + 2] = b.z; xv[4 * q + 3] = b.w;
  }
  float p[RR];
#pragma unroll
  for (int r = 0; r < RR; ++r) {
    float acc = A1B[r];
#pragma unroll
    for (int k = 0; k < CC; ++k) acc = fmaf(xv[k], A1[r * CC + k], acc);
    p[r] = fmaxf(acc, 0.0f);
  }
  const float4* hp = (const float4*)(h + (size_t)i * CC);
  const float4* sHp = (const float4*)(sumH + (size_t)g * CC);
  const float4* sH2p = (const float4*)(sumH2 + (size_t)g * CC);
  float4* op = (float4*)(out + (size_t)i * CC);
#pragma unroll 4
  for (int q = 0; q < 16; ++q) {
    float4 h4 = hp[q];
    float4 sH = sHp[q];
    float4 sH2 = sH2p[q];
    float hv[4] = {h4.x, h4.y, h4.z, h4.w};
    float sh[4] = {sH.x, sH.y, sH.z, sH.w};
    float sh2[4] = {sH2.x, sH2.y, sH2.z, sH2.w};
    float res[4];
#pragma unroll
    for (int u = 0; u < 4; ++u) {
      int c = q * 4 + u;
      float mu = sh[u] * rn;
      float t = PRM[3 * CC + c] * mu;
      float var = sh2[u] * rn - 2.0f * mu * t + t * t;
      float o = hv[u] - t;
      float y = fmaf(PRM[CC + c] * o, rsqrtf(var + EPSF), PRM[2 * CC + c]);
      float gacc = PRM[c];
#pragma unroll
      for (int r = 0; r < RR; ++r) gacc = fmaf(p[r], A2[c * RR + r], gacc);
      float gate = 1.0f / (1.0f + __expf(-gacc));
      res[u] = fmaxf(y + gate * xv[c], 0.0f);
    }
    op[q] = make_float4(res[0], res[1], res[2], res[3]);
  }
}

extern "C" void kernel_launch(void* const* d_in, const int* in_sizes, int n_in,
                              void* d_out, int out_size, void* d_ws, size_t ws_size,
                              hipStream_t stream) {
  const float* x        = (const float*)d_in[0];
  const int*   ei       = (const int*)d_in[1];
  const int*   batch    = (const int*)d_in[2];
  const float* Wl       = (const float*)d_in[3];
  const float* bl       = (const float*)d_in[4];
  const float* Wr       = (const float*)d_in[5];
  const float* gn_w     = (const float*)d_in[6];
  const float* gn_b     = (const float*)d_in[7];
  const float* gn_alpha = (const float*)d_in[8];
  const float* a1w      = (const float*)d_in[9];
  const float* a1b      = (const float*)d_in[10];
  const float* a2w      = (const float*)d_in[11];
  const float* a2b      = (const float*)d_in[12];
  float* out = (float*)d_out;

  // workspace layout (4B units)
  float*    h        = (float*)d_ws;                     // NN*CC
  unsigned* ebuf     = (unsigned*)(h + (size_t)NN * CC); // NE
  int*      csr      = (int*)(ebuf + NE);                // NE
  int*      rowptr   = csr + NE;                         // NN+1
  int*      bin_tot  = rowptr + NN + 1;                  // BINP  } zeroed
  float*    sumH     = (float*)(bin_tot + BINP);         // GG*CC } zeroed
  float*    sumH2    = sumH + GG * CC;                   // GG*CC } zeroed
  float*    cntg     = sumH2 + GG * CC;                  // GG    } zeroed
  int*      bin_base = (int*)(cntg + GG);                // BINS+1
  int*      cursor   = bin_base + BINS + 1;              // BINS

  size_t zbytes = ((size_t)BINP + 2 * GG * CC + GG) * sizeof(int);
  hipMemsetAsync((void*)bin_tot, 0, zbytes, stream);

  k_hist    <<<256, 256, 0, stream>>>(ei, bin_tot);
  k_scanbins<<<1, BINP, 0, stream>>>(bin_tot, bin_base, cursor, rowptr);
  k_phase1  <<<256, 256, 0, stream>>>(ei, cursor, ebuf);
  k_fill2   <<<BINS, 256, 0, stream>>>(ebuf, bin_base, rowptr, csr);
  k_gather  <<<(NN + 3) / 4, 256, 0, stream>>>(x, csr, rowptr, h);
  k_passA   <<<(NN + 255) / 256, 256, 0, stream>>>(x, h, rowptr, Wl, bl, Wr);
  k_stats   <<<((NN + 15) / 16 + 3) / 4, 256, 0, stream>>>(h, batch, sumH, sumH2, cntg);
  k_passC   <<<(NN + 255) / 256, 256, 0, stream>>>(h, x, batch, sumH, sumH2, cntg,
                                                   gn_w, gn_b, gn_alpha,
                                                   a1w, a1b, a2w, a2b, out);
}

// Round 11
// 206.205 us; speedup vs baseline: 3.1920x; 1.0643x over previous
//
#include <hip/hip_runtime.h>
#include <math.h>

#define NN 100000
#define NE 1200000
#define CC 64
#define GG 256
#define RR 8
#define EPSF 1e-5f
#define BINS 782   // ceil(NN/128), bin = dst >> 7
#define BINP 1024  // padded (pow2)
#define EPB 4688   // edges per hist/phase1 block (256 blocks)
#define QS 1028    // passA per-quarter LDS stride in floats (1024 + 4 -> banks 4q)

// ---------- hist: global per-bin edge counts ----------
__global__ __launch_bounds__(256) void k_hist(const int* __restrict__ ei,
                                              int* __restrict__ bin_total) {
  __shared__ int hist[BINP];
  for (int t = threadIdx.x; t < BINP; t += 256) hist[t] = 0;
  __syncthreads();
  int start = blockIdx.x * EPB;
  int end = start + EPB < NE ? start + EPB : NE;
  for (int e = start + threadIdx.x; e < end; e += 256)
    atomicAdd(&hist[ei[NE + e] >> 7], 1);
  __syncthreads();
  for (int t = threadIdx.x; t < BINP; t += 256)
    if (hist[t]) atomicAdd(&bin_total[t], hist[t]);
}

// ---------- scan bins -> bin_base (exclusive) + cursor; rowptr[NN]=NE ----------
__global__ __launch_bounds__(1024) void k_scanbins(const int* __restrict__ bin_total,
                                                   int* __restrict__ bin_base,
                                                   int* __restrict__ cursor,
                                                   int* __restrict__ rowptr) {
  __shared__ int sh[BINP];
  int t = threadIdx.x;
  int v = t < BINS ? bin_total[t] : 0;
  sh[t] = v;
  __syncthreads();
  for (int d = 1; d < BINP; d <<= 1) {
    int val = sh[t];
    int add = (t >= d) ? sh[t - d] : 0;
    __syncthreads();
    sh[t] = val + add;
    __syncthreads();
  }
  int excl = sh[t] - v;
  if (t < BINS) {
    bin_base[t] = excl;
    cursor[t] = excl;
  }
  if (t == 0) {
    bin_base[BINS] = NE;
    rowptr[NN] = NE;
  }
}

// ---------- phase1: packed (src<<7)|(dst&127) into bin-contiguous buckets ----------
__global__ __launch_bounds__(256) void k_phase1(const int* __restrict__ ei,
                                                int* __restrict__ cursor,
                                                unsigned* __restrict__ ebuf) {
  __shared__ int hist[BINP];
  __shared__ int base[BINP];
  for (int t = threadIdx.x; t < BINP; t += 256) hist[t] = 0;
  __syncthreads();
  int start = blockIdx.x * EPB;
  int end = start + EPB < NE ? start + EPB : NE;
  for (int e = start + threadIdx.x; e < end; e += 256)
    atomicAdd(&hist[ei[NE + e] >> 7], 1);
  __syncthreads();
  for (int t = threadIdx.x; t < BINP; t += 256) {
    int c = hist[t];
    base[t] = c ? atomicAdd(&cursor[t], c) : 0;
  }
  __syncthreads();
  for (int t = threadIdx.x; t < BINP; t += 256) hist[t] = 0;
  __syncthreads();
  for (int e = start + threadIdx.x; e < end; e += 256) {
    int src = ei[e], dst = ei[NE + e];
    int b = dst >> 7;
    int off = atomicAdd(&hist[b], 1);
    ebuf[base[b] + off] = ((unsigned)src << 7) | (unsigned)(dst & 127);
  }
}

// ---------- fill2: per-bin CSR (rowptr + coalesced csr) ----------
__global__ __launch_bounds__(256) void k_fill2(const unsigned* __restrict__ ebuf,
                                               const int* __restrict__ bin_base,
                                               int* __restrict__ rowptr,
                                               int* __restrict__ csr) {
  __shared__ int cnt[128];
  __shared__ int sc[128];
  int tid = threadIdx.x;
  int b = blockIdx.x;
  int s = bin_base[b], e = bin_base[b + 1];
  if (tid < 128) cnt[tid] = 0;
  __syncthreads();
  for (int i = s + tid; i < e; i += 256) atomicAdd(&cnt[ebuf[i] & 127], 1);
  __syncthreads();
  if (tid < 128) sc[tid] = cnt[tid];
  __syncthreads();
  for (int d = 1; d < 128; d <<= 1) {
    int v = (tid < 128) ? sc[tid] : 0;
    int a = (tid >= d && tid < 128) ? sc[tid - d] : 0;
    __syncthreads();
    if (tid < 128) sc[tid] = v + a;
    __syncthreads();
  }
  if (tid < 128) {
    sc[tid] -= cnt[tid];  // exclusive
    int node = (b << 7) + tid;
    if (node < NN) rowptr[node] = s + sc[tid];
    cnt[tid] = 0;
  }
  __syncthreads();
  for (int i = s + tid; i < e; i += 256) {
    unsigned v = ebuf[i];
    int dl = v & 127;
    int off = atomicAdd(&cnt[dl], 1);
    csr[s + sc[dl] + off] = (int)(v >> 7);
  }
}

// ---------- gather: agg[i] = sum of x[src] (wave per node, 8-deep MLP) ----------
__global__ __launch_bounds__(256) void k_gather(const float* __restrict__ x,
                                                const int* __restrict__ csr,
                                                const int* __restrict__ rowptr,
                                                float* __restrict__ h) {
  int w = blockIdx.x * 4 + (threadIdx.x >> 6);
  int lane = threadIdx.x & 63;
  if (w >= NN) return;
  int s = rowptr[w], e = rowptr[w + 1];
  float acc = 0.0f;
  for (int j0 = s; j0 < e; j0 += 8) {
    int idx[8];
#pragma unroll
    for (int u = 0; u < 8; ++u) {
      int j = j0 + u;
      idx[u] = csr[j < e ? j : e - 1];  // wave-uniform -> s_load
    }
    float v[8];
#pragma unroll
    for (int u = 0; u < 8; ++u) v[u] = x[(size_t)idx[u] * CC + lane];
#pragma unroll
    for (int u = 0; u < 8; ++u) acc += (j0 + u < e) ? v[u] : 0.0f;
  }
  h[(size_t)w * CC + lane] = acc;
}

// ---------- passA: h = (agg/deg)@Wl^T + bl + x@Wr^T, in place over h ----------
// Wave-tile = 64 nodes; lane (n=l&15, q=l>>4): nodes n+m*16, output quarter q.
// Two separable passes (agg@Wl then x@Wr) into one acc[4][16]. Each pass
// streams full 64B lines into regs (A[4][4] f4, live per-iteration only) ->
// every cache line fully consumed in-iteration, no L1 reuse needed.
// Weights in LDS [mat][q][j][quad], quarter stride QS=1028 floats -> the 4
// per-wave broadcast addrs land in banks {0,4,8,12}. ~165 VGPR, no spill.
__global__ __launch_bounds__(256) void k_passA(
    const float* __restrict__ x, float* h, const int* __restrict__ rowptr,
    const float* __restrict__ Wl, const float* __restrict__ bl,
    const float* __restrict__ Wr) {
  __shared__ float WLs[4 * QS];
  __shared__ float WRs[4 * QS];
  __shared__ float bls[CC];
  for (int idx = threadIdx.x; idx < CC * CC; idx += 256) {
    int c = idx >> 6, k = idx & 63;
    int qq = c >> 4, j = c & 15;
    WLs[qq * QS + j * 64 + k] = Wl[idx];
    WRs[qq * QS + j * 64 + k] = Wr[idx];
  }
  if (threadIdx.x < CC) bls[threadIdx.x] = bl[threadIdx.x];
  __syncthreads();

  int lane = threadIdx.x & 63;
  int wave = threadIdx.x >> 6;
  int n = lane & 15;
  int q = lane >> 4;
  int i0 = blockIdx.x * 256 + wave * 64 + n;  // + m*16
  const float4* wl = (const float4*)(WLs + q * QS);  // + j*16 + quad
  const float4* wr = (const float4*)(WRs + q * QS);

  const float4* ap[4];
  const float4* xp[4];
  float inv[4];
#pragma unroll
  for (int m = 0; m < 4; ++m) {
    int i = i0 + m * 16;
    int c = i < NN ? i : NN - 1;
    inv[m] = 1.0f / fmaxf((float)(rowptr[c + 1] - rowptr[c]), 1.0f);
    ap[m] = (const float4*)(h + (size_t)c * CC);
    xp[m] = (const float4*)(x + (size_t)c * CC);
  }

  float acc[4][16];
#pragma unroll
  for (int j = 0; j < 16; ++j) {
    float b = bls[q * 16 + j];
#pragma unroll
    for (int m = 0; m < 4; ++m) acc[m][j] = b;
  }

  // pass 1: acc += (h*inv) @ Wl^T   (stream h lines, full-line consume)
  for (int kbl = 0; kbl < 4; ++kbl) {
    float4 A[4][4];
#pragma unroll
    for (int m = 0; m < 4; ++m) {
#pragma unroll
      for (int t = 0; t < 4; ++t) {
        float4 v = ap[m][kbl * 4 + t];
        A[m][t] = make_float4(v.x * inv[m], v.y * inv[m], v.z * inv[m], v.w * inv[m]);
      }
    }
#pragma unroll
    for (int t = 0; t < 4; ++t) {
#pragma unroll
      for (int j = 0; j < 16; ++j) {
        float4 w = wl[j * 16 + kbl * 4 + t];
#pragma unroll
        for (int m = 0; m < 4; ++m) {
          float v = acc[m][j];
          v = fmaf(A[m][t].x, w.x, v);
          v = fmaf(A[m][t].y, w.y, v);
          v = fmaf(A[m][t].z, w.z, v);
          v = fmaf(A[m][t].w, w.w, v);
          acc[m][j] = v;
        }
      }
    }
  }

  // pass 2: acc += x @ Wr^T
  for (int kbl = 0; kbl < 4; ++kbl) {
    float4 A[4][4];
#pragma unroll
    for (int m = 0; m < 4; ++m) {
#pragma unroll
      for (int t = 0; t < 4; ++t) A[m][t] = xp[m][kbl * 4 + t];
    }
#pragma unroll
    for (int t = 0; t < 4; ++t) {
#pragma unroll
      for (int j = 0; j < 16; ++j) {
        float4 w = wr[j * 16 + kbl * 4 + t];
#pragma unroll
        for (int m = 0; m < 4; ++m) {
          float v = acc[m][j];
          v = fmaf(A[m][t].x, w.x, v);
          v = fmaf(A[m][t].y, w.y, v);
          v = fmaf(A[m][t].z, w.z, v);
          v = fmaf(A[m][t].w, w.w, v);
          acc[m][j] = v;
        }
      }
    }
  }

#pragma unroll
  for (int m = 0; m < 4; ++m) {
    int i = i0 + m * 16;
    if (i < NN) {
      float4* hp = (float4*)(h + (size_t)i * CC + q * 16);
#pragma unroll
      for (int r = 0; r < 4; ++r)
        hp[r] = make_float4(acc[m][4 * r], acc[m][4 * r + 1],
                            acc[m][4 * r + 2], acc[m][4 * r + 3]);
    }
  }
}

// ---------- stats: segmented per-graph sum(h), sum(h^2), count (batch sorted) ----------
__global__ __launch_bounds__(256) void k_stats(const float* __restrict__ h,
                                               const int* __restrict__ batch,
                                               float* __restrict__ sumH,
                                               float* __restrict__ sumH2,
                                               float* __restrict__ cntg) {
  int w = blockIdx.x * 4 + (threadIdx.x >> 6);
  int lane = threadIdx.x & 63;
  int i0 = w * 16;
  if (i0 >= NN) return;
  int iend = i0 + 16 < NN ? i0 + 16 : NN;
  int gcur = batch[i0];
  float aH = 0.0f, aH2 = 0.0f;
  int run = 0;
  for (int i = i0; i < iend; ++i) {
    int g = batch[i];  // wave-uniform
    if (g != gcur) {
      atomicAdd(&sumH[(size_t)gcur * CC + lane], aH);
      atomicAdd(&sumH2[(size_t)gcur * CC + lane], aH2);
      if (lane == 0) atomicAdd(&cntg[gcur], (float)run);
      aH = 0.0f; aH2 = 0.0f; run = 0;
      gcur = g;
    }
    float v = h[(size_t)i * CC + lane];
    aH += v;
    aH2 += v * v;
    run++;
  }
  atomicAdd(&sumH[(size_t)gcur * CC + lane], aH);
  atomicAdd(&sumH2[(size_t)gcur * CC + lane], aH2);
  if (lane == 0) atomicAdd(&cntg[gcur], (float)run);
}

// ---------- passC: normalize (closed-form var) + gate + residual + relu ----------
__global__ __launch_bounds__(256) void k_passC(
    const float* __restrict__ h, const float* __restrict__ x,
    const int* __restrict__ batch, const float* __restrict__ sumH,
    const float* __restrict__ sumH2, const float* __restrict__ cntg,
    const float* __restrict__ gw, const float* __restrict__ gb,
    const float* __restrict__ alpha, const float* __restrict__ a1w,
    const float* __restrict__ a1b, const float* __restrict__ a2w,
    const float* __restrict__ a2b, float* __restrict__ out) {
  __shared__ float A1[RR * CC];
  __shared__ float A2[CC * RR];
  __shared__ float A1B[RR];
  __shared__ float PRM[4 * CC];   // a2b | gw | gb | alpha
  for (int idx = threadIdx.x; idx < RR * CC; idx += 256) {
    A1[idx] = a1w[idx];
    A2[idx] = a2w[idx];
  }
  if (threadIdx.x < RR) A1B[threadIdx.x] = a1b[threadIdx.x];
  if (threadIdx.x < CC) {
    PRM[threadIdx.x] = a2b[threadIdx.x];
    PRM[CC + threadIdx.x] = gw[threadIdx.x];
    PRM[2 * CC + threadIdx.x] = gb[threadIdx.x];
    PRM[3 * CC + threadIdx.x] = alpha[threadIdx.x];
  }
  __syncthreads();

  int i = blockIdx.x * 256 + threadIdx.x;
  if (i >= NN) return;
  int g = batch[i];
  float rn = 1.0f / fmaxf(cntg[g], 1.0f);
  float xv[CC];
  const float4* xp = (const float4*)(x + (size_t)i * CC);
#pragma unroll
  for (int q = 0; q < 16; ++q) {
    float4 b = xp[q];
    xv[4 * q] = b.x; xv[4 * q + 1] = b.y; xv[4 * q + 2] = b.z; xv[4 * q + 3] = b.w;
  }
  float p[RR];
#pragma unroll
  for (int r = 0; r < RR; ++r) {
    float acc = A1B[r];
#pragma unroll
    for (int k = 0; k < CC; ++k) acc = fmaf(xv[k], A1[r * CC + k], acc);
    p[r] = fmaxf(acc, 0.0f);
  }
  const float4* hp = (const float4*)(h + (size_t)i * CC);
  const float4* sHp = (const float4*)(sumH + (size_t)g * CC);
  const float4* sH2p = (const float4*)(sumH2 + (size_t)g * CC);
  float4* op = (float4*)(out + (size_t)i * CC);
#pragma unroll 4
  for (int q = 0; q < 16; ++q) {
    float4 h4 = hp[q];
    float4 sH = sHp[q];
    float4 sH2 = sH2p[q];
    float hv[4] = {h4.x, h4.y, h4.z, h4.w};
    float sh[4] = {sH.x, sH.y, sH.z, sH.w};
    float sh2[4] = {sH2.x, sH2.y, sH2.z, sH2.w};
    float res[4];
#pragma unroll
    for (int u = 0; u < 4; ++u) {
      int c = q * 4 + u;
      float mu = sh[u] * rn;
      float t = PRM[3 * CC + c] * mu;
      float var = sh2[u] * rn - 2.0f * mu * t + t * t;
      float o = hv[u] - t;
      float y = fmaf(PRM[CC + c] * o, rsqrtf(var + EPSF), PRM[2 * CC + c]);
      float gacc = PRM[c];
#pragma unroll
      for (int r = 0; r < RR; ++r) gacc = fmaf(p[r], A2[c * RR + r], gacc);
      float gate = 1.0f / (1.0f + __expf(-gacc));
      res[u] = fmaxf(y + gate * xv[c], 0.0f);
    }
    op[q] = make_float4(res[0], res[1], res[2], res[3]);
  }
}

extern "C" void kernel_launch(void* const* d_in, const int* in_sizes, int n_in,
                              void* d_out, int out_size, void* d_ws, size_t ws_size,
                              hipStream_t stream) {
  const float* x        = (const float*)d_in[0];
  const int*   ei       = (const int*)d_in[1];
  const int*   batch    = (const int*)d_in[2];
  const float* Wl       = (const float*)d_in[3];
  const float* bl       = (const float*)d_in[4];
  const float* Wr       = (const float*)d_in[5];
  const float* gn_w     = (const float*)d_in[6];
  const float* gn_b     = (const float*)d_in[7];
  const float* gn_alpha = (const float*)d_in[8];
  const float* a1w      = (const float*)d_in[9];
  const float* a1b      = (const float*)d_in[10];
  const float* a2w      = (const float*)d_in[11];
  const float* a2b      = (const float*)d_in[12];
  float* out = (float*)d_out;

  // workspace layout (4B units)
  float*    h        = (float*)d_ws;                     // NN*CC
  unsigned* ebuf     = (unsigned*)(h + (size_t)NN * CC); // NE
  int*      csr      = (int*)(ebuf + NE);                // NE
  int*      rowptr   = csr + NE;                         // NN+1
  int*      bin_tot  = rowptr + NN + 1;                  // BINP  } zeroed
  float*    sumH     = (float*)(bin_tot + BINP);         // GG*CC } zeroed
  float*    sumH2    = sumH + GG * CC;                   // GG*CC } zeroed
  float*    cntg     = sumH2 + GG * CC;                  // GG    } zeroed
  int*      bin_base = (int*)(cntg + GG);                // BINS+1
  int*      cursor   = bin_base + BINS + 1;              // BINS

  size_t zbytes = ((size_t)BINP + 2 * GG * CC + GG) * sizeof(int);
  hipMemsetAsync((void*)bin_tot, 0, zbytes, stream);

  k_hist    <<<256, 256, 0, stream>>>(ei, bin_tot);
  k_scanbins<<<1, BINP, 0, stream>>>(bin_tot, bin_base, cursor, rowptr);
  k_phase1  <<<256, 256, 0, stream>>>(ei, cursor, ebuf);
  k_fill2   <<<BINS, 256, 0, stream>>>(ebuf, bin_base, rowptr, csr);
  k_gather  <<<(NN + 3) / 4, 256, 0, stream>>>(x, csr, rowptr, h);
  k_passA   <<<(NN + 255) / 256, 256, 0, stream>>>(x, h, rowptr, Wl, bl, Wr);
  k_stats   <<<((NN + 15) / 16 + 3) / 4, 256, 0, stream>>>(h, batch, sumH, sumH2, cntg);
  k_passC   <<<(NN + 255) / 256, 256, 0, stream>>>(h, x, batch, sumH, sumH2, cntg,
                                                   gn_w, gn_b, gn_alpha,
                                                   a1w, a1b, a2w, a2b, out);
}